// Round 1
// baseline (352.548 us; speedup 1.0000x reference)
//
#include <hip/hip_runtime.h>
#include <hip/hip_bf16.h>

#define DEV __device__ __forceinline__

typedef __attribute__((ext_vector_type(8))) short bf16x8;
typedef __attribute__((ext_vector_type(4))) float f32x4;
typedef __attribute__((ext_vector_type(4))) int int4v;

static constexpr int BATCH = 8;
static constexpr int SEQ   = 1024;
static constexpr int CDIM  = 1024;
static constexpr int NH    = 16;
static constexpr int HD    = 64;
static constexpr int N3    = 3072;

DEV short f2bf(float x) {
    __hip_bfloat16 h = __float2bfloat16(x);
    return __builtin_bit_cast(short, h);
}
DEV float bf2f(short x) {
    unsigned u = ((unsigned)(unsigned short)x) << 16;
    return __builtin_bit_cast(float, u);
}

// ---------------- fp32 -> bf16 bulk convert (8 elems/thread) ----------------
__global__ void k_f32_to_bf16(const float* __restrict__ in, short* __restrict__ out, int n) {
    int i = (blockIdx.x * blockDim.x + threadIdx.x) * 8;
    if (i >= n) return;
    float4 a = *(const float4*)(in + i);
    float4 b = *(const float4*)(in + i + 4);
    bf16x8 o;
    o[0] = f2bf(a.x); o[1] = f2bf(a.y); o[2] = f2bf(a.z); o[3] = f2bf(a.w);
    o[4] = f2bf(b.x); o[5] = f2bf(b.y); o[6] = f2bf(b.z); o[7] = f2bf(b.w);
    *(bf16x8*)(out + i) = o;
}

// ------------- fp32 [K][N] -> bf16 [N][K] tiled transpose -------------------
__global__ void k_transpose_f32_to_bf16(const float* __restrict__ in, short* __restrict__ out,
                                        int K, int N) {
    __shared__ float tile[32][33];
    int n0 = blockIdx.x * 32, k0 = blockIdx.y * 32;
    int tx = threadIdx.x, ty = threadIdx.y;  // 32 x 8
    for (int i = 0; i < 32; i += 8)
        tile[ty + i][tx] = in[(long)(k0 + ty + i) * N + n0 + tx];
    __syncthreads();
    for (int i = 0; i < 32; i += 8)
        out[(long)(n0 + ty + i) * K + k0 + tx] = f2bf(tile[tx][ty + i]);
}

// ---------------- bf16 GEMM: C[M][N] = A[M][K] * Bt[N][K]^T + bias ----------
template <bool OUT_BF16>
__global__ __launch_bounds__(256) void k_gemm(
    const short* __restrict__ A, const short* __restrict__ Bt,
    const float* __restrict__ bias, void* __restrict__ Cout,
    int M, int N, int K) {
    constexpr int BM = 128, BN = 128, BK = 32;
    constexpr int LDT = 40;  // padded row (elems): 80B rows -> conflict-free frag reads
    __shared__ short As[BM * LDT];
    __shared__ short Bs[BN * LDT];
    int tid = threadIdx.x;
    int nbn = N / BN;
    int bm = blockIdx.x / nbn, bn = blockIdx.x % nbn;
    int m0 = bm * BM, n0 = bn * BN;
    int w = tid >> 6, l = tid & 63;
    int wm = (w >> 1) * 64, wn = (w & 1) * 64;
    int lr = l & 15, lk = l >> 4;
    f32x4 acc[4][4] = {};
    for (int k0 = 0; k0 < K; k0 += BK) {
        for (int c = tid; c < BM * BK / 8; c += 256) {
            int row = c >> 2, cg = c & 3;
            *(int4v*)&As[row * LDT + cg * 8] = *(const int4v*)&A[(long)(m0 + row) * K + k0 + cg * 8];
            *(int4v*)&Bs[row * LDT + cg * 8] = *(const int4v*)&Bt[(long)(n0 + row) * K + k0 + cg * 8];
        }
        __syncthreads();
        bf16x8 af[4], bfr[4];
        for (int mi = 0; mi < 4; ++mi) af[mi]  = *(const bf16x8*)&As[(wm + mi * 16 + lr) * LDT + lk * 8];
        for (int ni = 0; ni < 4; ++ni) bfr[ni] = *(const bf16x8*)&Bs[(wn + ni * 16 + lr) * LDT + lk * 8];
        for (int mi = 0; mi < 4; ++mi)
            for (int ni = 0; ni < 4; ++ni)
                acc[mi][ni] = __builtin_amdgcn_mfma_f32_16x16x32_bf16(af[mi], bfr[ni], acc[mi][ni], 0, 0, 0);
        __syncthreads();
    }
    for (int mi = 0; mi < 4; ++mi)
        for (int ni = 0; ni < 4; ++ni) {
            int col = n0 + wn + ni * 16 + lr;
            float bv = bias[col];
            for (int r = 0; r < 4; ++r) {
                int row = m0 + wm + mi * 16 + lk * 4 + r;
                float v = acc[mi][ni][r] + bv;
                if (OUT_BF16) ((short*)Cout)[(long)row * N + col] = f2bf(v);
                else          ((float*)Cout)[(long)row * N + col] = v;
            }
        }
}

// ------------- per-head LayerNorm + RoPE + [B,S,3,H,D]->[B,H,S,D] -----------
__global__ __launch_bounds__(256) void k_ln_rope(
    const short* __restrict__ qkv,
    const float* __restrict__ qn_w, const float* __restrict__ qn_b,
    const float* __restrict__ kn_w, const float* __restrict__ kn_b,
    const float* __restrict__ fcos, const float* __restrict__ fsin,
    short* __restrict__ q, short* __restrict__ k, short* __restrict__ v) {
    int wave = (blockIdx.x * blockDim.x + threadIdx.x) >> 6;
    int lane = threadIdx.x & 63;
    int h = wave & 15;
    int tmp = wave >> 4;
    int which = tmp % 3;
    int bs = tmp / 3;              // b*SEQ + s
    int s = bs & 1023, b = bs >> 10;
    float x = bf2f(qkv[(long)bs * N3 + which * CDIM + h * HD + lane]);
    short* dst;
    float y;
    if (which == 2) {
        y = x; dst = v;
    } else {
        float mu = x;
        for (int o = 32; o > 0; o >>= 1) mu += __shfl_xor(mu, o);
        mu *= (1.f / 64.f);
        float d = x - mu;
        float var = d * d;
        for (int o = 32; o > 0; o >>= 1) var += __shfl_xor(var, o);
        var *= (1.f / 64.f);
        const float* wv = which ? kn_w : qn_w;
        const float* bb = which ? kn_b : qn_b;
        y = d * rsqrtf(var + 1e-6f) * wv[lane] + bb[lane];
        float c = fcos[s * HD + lane], sn = fsin[s * HD + lane];
        float partner = __shfl_xor(y, 1);
        float rot = (lane & 1) ? partner : -partner;   // even d: -x[d+1]; odd d: x[d-1]
        y = y * c + rot * sn;
        dst = which ? k : q;
    }
    dst[((long)(b * NH + h) * SEQ + s) * HD + lane] = f2bf(y);
}

// ---------------- flash attention: per (b,h), QBLK=64, KVB=64 ---------------
__global__ __launch_bounds__(256) void k_attn(
    const short* __restrict__ q, const short* __restrict__ k, const short* __restrict__ v,
    short* __restrict__ out /* [B,S,C] bf16 */) {
    constexpr int KVB = 64;
    __shared__ short Ks[KVB * 64];      // [kv][d], 128B rows, XOR-swizzled
    __shared__ short Vt[64 * KVB];      // [d][kv], 128B rows, XOR-swizzled
    __shared__ short Ps[4 * 16 * 64];   // per-wave P [16 q][64 kv], swizzled
    int tid = threadIdx.x, w = tid >> 6, l = tid & 63;
    int bh = blockIdx.x >> 4;
    int q0 = (blockIdx.x & 15) * 64;
    const short* qb = q + (long)bh * SEQ * HD;
    const short* kb = k + (long)bh * SEQ * HD;
    const short* vb = v + (long)bh * SEQ * HD;
    int lr = l & 15, lk = l >> 4;
    int qrow = q0 + w * 16 + lr;
    bf16x8 qA[2];
    qA[0] = *(const bf16x8*)&qb[(long)qrow * HD + lk * 8];
    qA[1] = *(const bf16x8*)&qb[(long)qrow * HD + 32 + lk * 8];
    f32x4 accO[4] = {};
    float m_run[4], l_run[4];
    for (int r = 0; r < 4; ++r) { m_run[r] = -1e30f; l_run[r] = 0.f; }
    char* pw = (char*)Ps + w * 2048;
    for (int t = 0; t < SEQ / KVB; ++t) {
        int kv0 = t * KVB;
        // stage K (16B chunks, swizzled)
        for (int c = tid; c < KVB * 8; c += 256) {
            int row = c >> 3, cg = c & 7;
            int4v val = *(const int4v*)&kb[(long)(kv0 + row) * HD + cg * 8];
            *(int4v*)((char*)Ks + row * 128 + ((cg * 16) ^ ((row & 7) << 4))) = val;
        }
        // stage V transposed (scalar writes, swizzled)
        for (int c = tid; c < KVB * 8; c += 256) {
            int row = c >> 3, cg = c & 7;
            int4v val = *(const int4v*)&vb[(long)(kv0 + row) * HD + cg * 8];
            short vs[8]; *(int4v*)vs = val;
            for (int j = 0; j < 8; ++j) {
                int d = cg * 8 + j;
                *(short*)((char*)Vt + d * 128 + ((row * 2) ^ ((d & 7) << 4))) = vs[j];
            }
        }
        __syncthreads();
        // scores S = Q K^T (C-layout: row = q = lk*4+r, col = kv = nf*16+lr)
        f32x4 sc[4];
        for (int nf = 0; nf < 4; ++nf) {
            f32x4 a = {};
            for (int ks = 0; ks < 2; ++ks) {
                int row = nf * 16 + lr;
                bf16x8 bfr = *(const bf16x8*)((const char*)Ks + row * 128 +
                                              (((lk * 16) + 64 * ks) ^ ((row & 7) << 4)));
                a = __builtin_amdgcn_mfma_f32_16x16x32_bf16(qA[ks], bfr, a, 0, 0, 0);
            }
            sc[nf] = a;
        }
        // online softmax (rows lk*4+r; reduce across the 16 lanes sharing a row)
        float p[4][4], alpha[4];
        for (int r = 0; r < 4; ++r) {
            float mt = -1e30f;
            for (int nf = 0; nf < 4; ++nf) { sc[nf][r] *= 0.125f; mt = fmaxf(mt, sc[nf][r]); }
            for (int o = 1; o < 16; o <<= 1) mt = fmaxf(mt, __shfl_xor(mt, o));
            float mn = fmaxf(m_run[r], mt);
            alpha[r] = __expf(m_run[r] - mn);
            float ls = 0.f;
            for (int nf = 0; nf < 4; ++nf) { p[r][nf] = __expf(sc[nf][r] - mn); ls += p[r][nf]; }
            for (int o = 1; o < 16; o <<= 1) ls += __shfl_xor(ls, o);
            l_run[r] = l_run[r] * alpha[r] + ls;
            m_run[r] = mn;
        }
        for (int df = 0; df < 4; ++df)
            for (int r = 0; r < 4; ++r) accO[df][r] *= alpha[r];
        // write P (C-layout) to per-wave LDS, re-read in A-layout
        for (int r = 0; r < 4; ++r) {
            int row = lk * 4 + r;
            for (int nf = 0; nf < 4; ++nf) {
                int col = nf * 16 + lr;
                *(short*)(pw + row * 128 + ((col * 2) ^ ((row & 7) << 4))) = f2bf(p[r][nf]);
            }
        }
        // O += P V
        for (int ks = 0; ks < 2; ++ks) {
            bf16x8 pa = *(const bf16x8*)(pw + lr * 128 + (((lk * 16) + 64 * ks) ^ ((lr & 7) << 4)));
            for (int df = 0; df < 4; ++df) {
                int d = df * 16 + lr;
                bf16x8 vf = *(const bf16x8*)((const char*)Vt + d * 128 +
                                             (((lk * 16) + 64 * ks) ^ ((d & 7) << 4)));
                accO[df] = __builtin_amdgcn_mfma_f32_16x16x32_bf16(pa, vf, accO[df], 0, 0, 0);
            }
        }
        __syncthreads();
    }
    int b = bh >> 4, h = bh & 15;
    for (int df = 0; df < 4; ++df) {
        int d = df * 16 + lr;
        for (int r = 0; r < 4; ++r) {
            int row = q0 + w * 16 + lk * 4 + r;
            float val = accO[df][r] / l_run[r];
            out[((long)(b * SEQ + row)) * CDIM + h * HD + d] = f2bf(val);
        }
    }
}

extern "C" void kernel_launch(void* const* d_in, const int* in_sizes, int n_in,
                              void* d_out, int out_size, void* d_ws, size_t ws_size,
                              hipStream_t stream) {
    const float* hidden = (const float*)d_in[0];
    const float* W_qkv  = (const float*)d_in[1];
    const float* b_qkv  = (const float*)d_in[2];
    const float* qn_w   = (const float*)d_in[3];
    const float* qn_b   = (const float*)d_in[4];
    const float* kn_w   = (const float*)d_in[5];
    const float* kn_b   = (const float*)d_in[6];
    const float* W_proj = (const float*)d_in[7];
    const float* b_proj = (const float*)d_in[8];
    const float* fcos   = (const float*)d_in[9];
    const float* fsin   = (const float*)d_in[10];
    float* out = (float*)d_out;

    const size_t SZ_HBF   = (size_t)BATCH * SEQ * CDIM * 2;   // 16.78 MB
    const size_t SZ_WQKVT = (size_t)N3 * CDIM * 2;            //  6.29 MB
    const size_t SZ_WPROJT= (size_t)CDIM * CDIM * 2;          //  2.10 MB
    const size_t SZ_QKV   = (size_t)BATCH * SEQ * N3 * 2;     // 50.33 MB
    const size_t SZ_HEAD  = (size_t)BATCH * NH * SEQ * HD * 2;// 16.78 MB each

    char* ws = (char*)d_ws;
    short* hbf    = (short*)ws; ws += SZ_HBF;
    short* wqkvT  = (short*)ws; ws += SZ_WQKVT;
    short* wprojT = (short*)ws; ws += SZ_WPROJT;
    short* qkv    = (short*)ws; ws += SZ_QKV;
    short* qh     = (short*)ws; ws += SZ_HEAD;
    short* kh     = (short*)ws; ws += SZ_HEAD;
    short* vh     = (short*)ws; ws += SZ_HEAD;
    short* attn_o = hbf;  // alias: hbf is dead after GEMM1

    size_t needed = SZ_HBF + SZ_WQKVT + SZ_WPROJT + SZ_QKV + 3 * SZ_HEAD;
    if (ws_size < needed) return;  // insufficient scratch; fail loudly via mismatch

    int nHid = BATCH * SEQ * CDIM;
    k_f32_to_bf16<<<nHid / 8 / 256, 256, 0, stream>>>(hidden, hbf, nHid);
    k_transpose_f32_to_bf16<<<dim3(N3 / 32, CDIM / 32), dim3(32, 8), 0, stream>>>(W_qkv, wqkvT, CDIM, N3);
    k_transpose_f32_to_bf16<<<dim3(CDIM / 32, CDIM / 32), dim3(32, 8), 0, stream>>>(W_proj, wprojT, CDIM, CDIM);

    // GEMM1: qkv = hidden @ W_qkv + b_qkv   [8192 x 3072]
    k_gemm<true><<<(BATCH * SEQ / 128) * (N3 / 128), 256, 0, stream>>>(
        hbf, wqkvT, b_qkv, qkv, BATCH * SEQ, N3, CDIM);

    // LN + RoPE + transpose to [B,H,S,D]
    int nWaves = BATCH * SEQ * 3 * NH;
    k_ln_rope<<<nWaves / 4, 256, 0, stream>>>(qkv, qn_w, qn_b, kn_w, kn_b, fcos, fsin, qh, kh, vh);

    // attention
    k_attn<<<BATCH * NH * (SEQ / 64), 256, 0, stream>>>(qh, kh, vh, attn_o);

    // GEMM2: out = attn_o @ W_proj + b_proj  [8192 x 1024] fp32
    k_gemm<false><<<(BATCH * SEQ / 128) * (CDIM / 128), 256, 0, stream>>>(
        attn_o, wprojT, b_proj, out, BATCH * SEQ, CDIM, CDIM);
}

// Round 2
// 245.496 us; speedup vs baseline: 1.4361x; 1.4361x over previous
//
#include <hip/hip_runtime.h>
#include <hip/hip_bf16.h>

#define DEV __device__ __forceinline__

typedef __attribute__((ext_vector_type(8))) short bf16x8;
typedef __attribute__((ext_vector_type(4))) short short4v;
typedef __attribute__((ext_vector_type(4))) float f32x4;
typedef __attribute__((ext_vector_type(4))) int int4v;

static constexpr int BATCH = 8;
static constexpr int SEQ   = 1024;
static constexpr int CDIM  = 1024;
static constexpr int NH    = 16;
static constexpr int HD    = 64;
static constexpr int N3    = 3072;

DEV short f2bf(float x) {
    __hip_bfloat16 h = __float2bfloat16(x);
    return __builtin_bit_cast(short, h);
}
DEV float bf2f(short x) {
    unsigned u = ((unsigned)(unsigned short)x) << 16;
    return __builtin_bit_cast(float, u);
}

typedef __attribute__((address_space(1))) const unsigned gas_u32;
typedef __attribute__((address_space(3))) unsigned las_u32;
DEV void gll16(const void* g, void* l) {
    __builtin_amdgcn_global_load_lds((gas_u32*)g, (las_u32*)l, 16, 0, 0);
}

// ---------------- fp32 -> bf16 bulk convert (8 elems/thread) ----------------
__global__ void k_f32_to_bf16(const float* __restrict__ in, short* __restrict__ out, int n) {
    int i = (blockIdx.x * blockDim.x + threadIdx.x) * 8;
    if (i >= n) return;
    float4 a = *(const float4*)(in + i);
    float4 b = *(const float4*)(in + i + 4);
    bf16x8 o;
    o[0] = f2bf(a.x); o[1] = f2bf(a.y); o[2] = f2bf(a.z); o[3] = f2bf(a.w);
    o[4] = f2bf(b.x); o[5] = f2bf(b.y); o[6] = f2bf(b.z); o[7] = f2bf(b.w);
    *(bf16x8*)(out + i) = o;
}

// ------------- fp32 [K][N] -> bf16 [N][K] tiled transpose -------------------
__global__ void k_transpose_f32_to_bf16(const float* __restrict__ in, short* __restrict__ out,
                                        int K, int N) {
    __shared__ float tile[32][33];
    int n0 = blockIdx.x * 32, k0 = blockIdx.y * 32;
    int tx = threadIdx.x, ty = threadIdx.y;  // 32 x 8
    for (int i = 0; i < 32; i += 8)
        tile[ty + i][tx] = in[(long)(k0 + ty + i) * N + n0 + tx];
    __syncthreads();
    for (int i = 0; i < 32; i += 8)
        out[(long)(n0 + ty + i) * K + k0 + tx] = f2bf(tile[tx][ty + i]);
}

// ----- V^T extraction: qkv[b,s,2C+h*64+d] -> vt[b,h,d,s]  (bf16) ------------
__global__ __launch_bounds__(256) void k_vt(const short* __restrict__ qkv, short* __restrict__ vt) {
    __shared__ short tile[64][72];  // 144B rows (16B-aligned), pad kills write/read conflicts
    int bid = blockIdx.x;
    int st = bid & 15, bh = bid >> 4;
    int h = bh & 15, b = bh >> 4;
    int s0 = st * 64;
    int tid = threadIdx.x;
    const short* src = qkv + (size_t)b * SEQ * N3 + 2 * CDIM + h * HD;
    for (int c = tid; c < 512; c += 256) {
        int sr = c >> 3, cg = c & 7;
        *(int4v*)&tile[sr][cg * 8] = *(const int4v*)&src[(size_t)(s0 + sr) * N3 + cg * 8];
    }
    __syncthreads();
    short* dst = vt + (size_t)bh * HD * SEQ + s0;
    for (int c = tid; c < 512; c += 256) {
        int d = c >> 3, sg = c & 7;
        short tmp[8];
#pragma unroll
        for (int j = 0; j < 8; ++j) tmp[j] = tile[sg * 8 + j][d];
        *(int4v*)&dst[(size_t)d * SEQ + sg * 8] = *(const int4v*)tmp;
    }
}

// --------- bf16 GEMM (m97 structure): C = A[M][K] * Bt[N][K]^T + bias -------
template <bool OUT_BF16>
__global__ __launch_bounds__(256) void k_gemm(
    const short* __restrict__ A, const short* __restrict__ Bt,
    const float* __restrict__ bias, void* __restrict__ Cout,
    int M, int N, int K) {
    constexpr int BM = 128, BN = 128, BK = 32;
    __shared__ short As[BM * BK];
    __shared__ short Bs[BN * BK];
    int tid = threadIdx.x;
    int nbn = N / BN;
    int bm = blockIdx.x / nbn, bn = blockIdx.x % nbn;
    int m0 = bm * BM, n0 = bn * BN;
    int w = tid >> 6, l = tid & 63;
    int wm = (w >> 1) * 64, wn = (w & 1) * 64;
    int lr = l & 15, lk = l >> 4;
    f32x4 acc[4][4] = {};
    int rowS = w * 32 + (l >> 2);   // staging row (lane covers 16B: 8 elems of k)
    int colS = (l & 3) * 8;
    for (int k0 = 0; k0 < K; k0 += BK) {
        const short* ga = A  + (size_t)(m0 + rowS) * K + k0 + colS;
        const short* gb = Bt + (size_t)(n0 + rowS) * K + k0 + colS;
        gll16(ga,               &As[(w * 32) * BK]);
        gll16(ga + 16 * K,      &As[(w * 32 + 16) * BK]);
        gll16(gb,               &Bs[(w * 32) * BK]);
        gll16(gb + 16 * K,      &Bs[(w * 32 + 16) * BK]);
        __syncthreads();
        bf16x8 af[4], bfr[4];
#pragma unroll
        for (int mi = 0; mi < 4; ++mi) af[mi]  = *(const bf16x8*)&As[(wm + mi * 16 + lr) * BK + lk * 8];
#pragma unroll
        for (int ni = 0; ni < 4; ++ni) bfr[ni] = *(const bf16x8*)&Bs[(wn + ni * 16 + lr) * BK + lk * 8];
#pragma unroll
        for (int mi = 0; mi < 4; ++mi)
#pragma unroll
            for (int ni = 0; ni < 4; ++ni)
                acc[mi][ni] = __builtin_amdgcn_mfma_f32_16x16x32_bf16(af[mi], bfr[ni], acc[mi][ni], 0, 0, 0);
        __syncthreads();
    }
#pragma unroll
    for (int mi = 0; mi < 4; ++mi)
#pragma unroll
        for (int ni = 0; ni < 4; ++ni) {
            int col = n0 + wn + ni * 16 + lr;
            float bv = bias[col];
#pragma unroll
            for (int r = 0; r < 4; ++r) {
                int row = m0 + wm + mi * 16 + lk * 4 + r;
                float v = acc[mi][ni][r] + bv;
                if (OUT_BF16) ((short*)Cout)[(size_t)row * N + col] = f2bf(v);
                else          ((float*)Cout)[(size_t)row * N + col] = v;
            }
        }
}

// ------------- per-head LayerNorm + RoPE (q,k only) -> [B,H,S,D] ------------
__global__ __launch_bounds__(256) void k_ln_rope(
    const short* __restrict__ qkv,
    const float* __restrict__ qn_w, const float* __restrict__ qn_b,
    const float* __restrict__ kn_w, const float* __restrict__ kn_b,
    const float* __restrict__ fcos, const float* __restrict__ fsin,
    short* __restrict__ q, short* __restrict__ k) {
    int wave = (blockIdx.x * blockDim.x + threadIdx.x) >> 6;
    int lane = threadIdx.x & 63;
    int h = wave & 15;
    int tmp = wave >> 4;
    int which = tmp & 1;
    int bs = tmp >> 1;             // b*SEQ + s
    int s = bs & 1023, b = bs >> 10;
    float x = bf2f(qkv[(size_t)bs * N3 + which * CDIM + h * HD + lane]);
    float mu = x;
    for (int o = 32; o > 0; o >>= 1) mu += __shfl_xor(mu, o);
    mu *= (1.f / 64.f);
    float d = x - mu;
    float var = d * d;
    for (int o = 32; o > 0; o >>= 1) var += __shfl_xor(var, o);
    var *= (1.f / 64.f);
    const float* wv = which ? kn_w : qn_w;
    const float* bb = which ? kn_b : qn_b;
    float y = d * rsqrtf(var + 1e-6f) * wv[lane] + bb[lane];
    float c = fcos[s * HD + lane], sn = fsin[s * HD + lane];
    float partner = __shfl_xor(y, 1);
    float rot = (lane & 1) ? partner : -partner;
    y = y * c + rot * sn;
    short* dst = which ? k : q;
    dst[((size_t)(b * NH + h) * SEQ + s) * HD + lane] = f2bf(y);
}

// --- flash attention, swapped-QK^T (S^T = K Q^T), lane-local softmax --------
__global__ __launch_bounds__(256) void k_attn(
    const short* __restrict__ q, const short* __restrict__ k, const short* __restrict__ vt,
    short* __restrict__ out /* [B,S,C] bf16 */) {
    constexpr int KVB = 64;
    __shared__ short Ks[KVB * 64];   // [kv][d], 128B rows, XOR-swizzled
    __shared__ short Vs[64 * KVB];   // [d][kv], 128B rows, XOR-swizzled
    int tid = threadIdx.x, w = tid >> 6, l = tid & 63;
    // XCD swizzle: 16 q-blocks of a head stay on one XCD's L2
    int bid = blockIdx.x;
    int swz = (bid & 7) * 256 + (bid >> 3);   // grid = 2048
    int bh = swz >> 4;
    int q0 = (swz & 15) * 64;
    const short* qb = q  + (size_t)bh * SEQ * HD;
    const short* kb = k  + (size_t)bh * SEQ * HD;
    const short* vb = vt + (size_t)bh * HD * SEQ;
    int lr = l & 15, lk = l >> 4;
    int qrow = q0 + w * 16 + lr;
    bf16x8 qB[2];
    qB[0] = *(const bf16x8*)&qb[(size_t)qrow * HD + lk * 8];
    qB[1] = *(const bf16x8*)&qb[(size_t)qrow * HD + 32 + lk * 8];
    f32x4 accO[4] = {};
    float m_run = -1e30f, l_run = 0.f;
    int g0 = 2 * (lk & 1);
    bool hi = (lk >> 1) != 0;
    for (int t = 0; t < SEQ / KVB; ++t) {
        int kv0 = t * KVB;
        // stage K [kv][64] and V^T [d][64kv] — pure 16B vector ops, swizzled
        for (int c = tid; c < 512; c += 256) {
            int row = c >> 3, cg = c & 7;
            int4v kvv = *(const int4v*)&kb[(size_t)(kv0 + row) * HD + cg * 8];
            *(int4v*)((char*)Ks + row * 128 + ((cg * 16) ^ ((row & 7) << 4))) = kvv;
            int4v vvv = *(const int4v*)&vb[(size_t)row * SEQ + kv0 + cg * 8];
            *(int4v*)((char*)Vs + row * 128 + ((cg * 16) ^ ((row & 7) << 4))) = vvv;
        }
        __syncthreads();
        // S^T[kv][q] = K Q^T : A=K-frag, B=Q-frag. Lane holds 16 kv for q=q0w+lr.
        f32x4 sc[4];
#pragma unroll
        for (int nf = 0; nf < 4; ++nf) {
            f32x4 a = {};
#pragma unroll
            for (int ks = 0; ks < 2; ++ks) {
                int row = nf * 16 + lr;
                bf16x8 kf = *(const bf16x8*)((const char*)Ks + row * 128 +
                                             ((ks * 64 + lk * 16) ^ ((row & 7) << 4)));
                a = __builtin_amdgcn_mfma_f32_16x16x32_bf16(kf, qB[ks], a, 0, 0, 0);
            }
            sc[nf] = a;
        }
        // online softmax: all per-lane; cross only via 4-lane-group shfl (16,32)
        float ps[4][4];
        float mt = -1e30f;
#pragma unroll
        for (int nf = 0; nf < 4; ++nf)
#pragma unroll
            for (int r = 0; r < 4; ++r) { ps[nf][r] = sc[nf][r] * 0.125f; mt = fmaxf(mt, ps[nf][r]); }
        mt = fmaxf(mt, __shfl_xor(mt, 16));
        mt = fmaxf(mt, __shfl_xor(mt, 32));
        float mn = fmaxf(m_run, mt);
        float alpha = __expf(m_run - mn);
        float ls = 0.f;
#pragma unroll
        for (int nf = 0; nf < 4; ++nf)
#pragma unroll
            for (int r = 0; r < 4; ++r) { ps[nf][r] = __expf(ps[nf][r] - mn); ls += ps[nf][r]; }
        ls += __shfl_xor(ls, 16);
        ls += __shfl_xor(ls, 32);
        l_run = l_run * alpha + ls;
        m_run = mn;
#pragma unroll
        for (int df = 0; df < 4; ++df)
#pragma unroll
            for (int r = 0; r < 4; ++r) accO[df][r] *= alpha;
        // pack P to bf16 words: pwd[nf][jj] = kv {16nf+4*lk+2jj, +1} for q=lr
        unsigned pwd[4][2];
#pragma unroll
        for (int nf = 0; nf < 4; ++nf)
#pragma unroll
            for (int jj = 0; jj < 2; ++jj)
                pwd[nf][jj] = (unsigned)(unsigned short)f2bf(ps[nf][2 * jj]) |
                              ((unsigned)(unsigned short)f2bf(ps[nf][2 * jj + 1]) << 16);
        // PV: O^T[d][q] += V^T P ; P B-frags assembled via register shuffles
#pragma unroll
        for (int c = 0; c < 2; ++c) {
            unsigned wds[4];
#pragma unroll
            for (int w2 = 0; w2 < 4; ++w2) {
                int src = lr + 16 * (g0 + (w2 >> 1));
                unsigned a0 = (unsigned)__shfl((int)pwd[2 * c][w2 & 1], src);
                unsigned a1 = (unsigned)__shfl((int)pwd[2 * c + 1][w2 & 1], src);
                wds[w2] = hi ? a1 : a0;
            }
            int4v wi = { (int)wds[0], (int)wds[1], (int)wds[2], (int)wds[3] };
            bf16x8 pf = __builtin_bit_cast(bf16x8, wi);
#pragma unroll
            for (int df = 0; df < 4; ++df) {
                int row = df * 16 + lr;
                bf16x8 vf = *(const bf16x8*)((const char*)Vs + row * 128 +
                                             ((c * 64 + lk * 16) ^ ((row & 7) << 4)));
                accO[df] = __builtin_amdgcn_mfma_f32_16x16x32_bf16(vf, pf, accO[df], 0, 0, 0);
            }
        }
        __syncthreads();
    }
    // epilogue: accO[df][r] = O^T[d = df*16 + lk*4 + r][q = q0 + w*16 + lr]
    float inv = 1.f / l_run;
    int b = bh >> 4, h = bh & 15;
    int qg = q0 + w * 16 + lr;
#pragma unroll
    for (int df = 0; df < 4; ++df) {
        short4v o4;
#pragma unroll
        for (int r = 0; r < 4; ++r) o4[r] = f2bf(accO[df][r] * inv);
        *(short4v*)&out[((size_t)(b * SEQ + qg)) * CDIM + h * HD + df * 16 + lk * 4] = o4;
    }
}

extern "C" void kernel_launch(void* const* d_in, const int* in_sizes, int n_in,
                              void* d_out, int out_size, void* d_ws, size_t ws_size,
                              hipStream_t stream) {
    const float* hidden = (const float*)d_in[0];
    const float* W_qkv  = (const float*)d_in[1];
    const float* b_qkv  = (const float*)d_in[2];
    const float* qn_w   = (const float*)d_in[3];
    const float* qn_b   = (const float*)d_in[4];
    const float* kn_w   = (const float*)d_in[5];
    const float* kn_b   = (const float*)d_in[6];
    const float* W_proj = (const float*)d_in[7];
    const float* b_proj = (const float*)d_in[8];
    const float* fcos   = (const float*)d_in[9];
    const float* fsin   = (const float*)d_in[10];
    float* out = (float*)d_out;

    const size_t SZ_HBF    = (size_t)BATCH * SEQ * CDIM * 2;
    const size_t SZ_WQKVT  = (size_t)N3 * CDIM * 2;
    const size_t SZ_WPROJT = (size_t)CDIM * CDIM * 2;
    const size_t SZ_QKV    = (size_t)BATCH * SEQ * N3 * 2;
    const size_t SZ_HEAD   = (size_t)BATCH * NH * SEQ * HD * 2;

    char* ws = (char*)d_ws;
    short* hbf    = (short*)ws; ws += SZ_HBF;
    short* wqkvT  = (short*)ws; ws += SZ_WQKVT;
    short* wprojT = (short*)ws; ws += SZ_WPROJT;
    short* qkv    = (short*)ws; ws += SZ_QKV;
    short* qh     = (short*)ws; ws += SZ_HEAD;
    short* kh     = (short*)ws; ws += SZ_HEAD;
    short* vt     = (short*)ws; ws += SZ_HEAD;
    short* attn_o = hbf;  // alias: hbf dead after GEMM1

    size_t needed = SZ_HBF + SZ_WQKVT + SZ_WPROJT + SZ_QKV + 3 * SZ_HEAD;
    if (ws_size < needed) return;

    int nHid = BATCH * SEQ * CDIM;
    k_f32_to_bf16<<<nHid / 8 / 256, 256, 0, stream>>>(hidden, hbf, nHid);
    k_transpose_f32_to_bf16<<<dim3(N3 / 32, CDIM / 32), dim3(32, 8), 0, stream>>>(W_qkv, wqkvT, CDIM, N3);
    k_transpose_f32_to_bf16<<<dim3(CDIM / 32, CDIM / 32), dim3(32, 8), 0, stream>>>(W_proj, wprojT, CDIM, CDIM);

    // GEMM1: qkv = hidden @ W_qkv + b_qkv   [8192 x 3072]
    k_gemm<true><<<(BATCH * SEQ / 128) * (N3 / 128), 256, 0, stream>>>(
        hbf, wqkvT, b_qkv, qkv, BATCH * SEQ, N3, CDIM);

    // LN + RoPE for q,k -> [B,H,S,D]; V^T extracted separately
    int nWaves = BATCH * SEQ * 2 * NH;
    k_ln_rope<<<nWaves / 4, 256, 0, stream>>>(qkv, qn_w, qn_b, kn_w, kn_b, fcos, fsin, qh, kh);
    k_vt<<<BATCH * NH * (SEQ / 64), 256, 0, stream>>>(qkv, vt);

    // attention
    k_attn<<<BATCH * NH * (SEQ / 64), 256, 0, stream>>>(qh, kh, vt, attn_o);

    // GEMM2: out = attn_o @ W_proj + b_proj  [8192 x 1024] fp32
    k_gemm<false><<<(BATCH * SEQ / 128) * (CDIM / 128), 256, 0, stream>>>(
        attn_o, wprojT, b_proj, out, BATCH * SEQ, CDIM, CDIM);
}

// Round 3
// 230.365 us; speedup vs baseline: 1.5304x; 1.0657x over previous
//
#include <hip/hip_runtime.h>
#include <hip/hip_bf16.h>

#define DEV __device__ __forceinline__

typedef __attribute__((ext_vector_type(8))) short bf16x8;
typedef __attribute__((ext_vector_type(4))) short short4v;
typedef __attribute__((ext_vector_type(4))) float f32x4;
typedef __attribute__((ext_vector_type(4))) int int4v;

static constexpr int BATCH = 8;
static constexpr int SEQ   = 1024;
static constexpr int CDIM  = 1024;
static constexpr int NH    = 16;
static constexpr int HD    = 64;
static constexpr int N3    = 3072;

DEV short f2bf(float x) {
    __hip_bfloat16 h = __float2bfloat16(x);
    return __builtin_bit_cast(short, h);
}
DEV float bf2f(short x) {
    unsigned u = ((unsigned)(unsigned short)x) << 16;
    return __builtin_bit_cast(float, u);
}
DEV float exp2_hw(float x) {  // v_exp_f32 computes 2^x natively
    float r;
    asm("v_exp_f32 %0, %1" : "=v"(r) : "v"(x));
    return r;
}

typedef __attribute__((address_space(1))) const unsigned gas_u32;
typedef __attribute__((address_space(3))) unsigned las_u32;
DEV void gll16(const void* g, void* l) {
    __builtin_amdgcn_global_load_lds((gas_u32*)g, (las_u32*)l, 16, 0, 0);
}

// ---------------- fp32 -> bf16 bulk convert (8 elems/thread) ----------------
__global__ void k_f32_to_bf16(const float* __restrict__ in, short* __restrict__ out, int n) {
    int i = (blockIdx.x * blockDim.x + threadIdx.x) * 8;
    if (i >= n) return;
    float4 a = *(const float4*)(in + i);
    float4 b = *(const float4*)(in + i + 4);
    bf16x8 o;
    o[0] = f2bf(a.x); o[1] = f2bf(a.y); o[2] = f2bf(a.z); o[3] = f2bf(a.w);
    o[4] = f2bf(b.x); o[5] = f2bf(b.y); o[6] = f2bf(b.z); o[7] = f2bf(b.w);
    *(bf16x8*)(out + i) = o;
}

// ------------- fp32 [K][N] -> bf16 [N][K] tiled transpose -------------------
__global__ void k_transpose_f32_to_bf16(const float* __restrict__ in, short* __restrict__ out,
                                        int K, int N) {
    __shared__ float tile[32][33];
    int n0 = blockIdx.x * 32, k0 = blockIdx.y * 32;
    int tx = threadIdx.x, ty = threadIdx.y;  // 32 x 8
    for (int i = 0; i < 32; i += 8)
        tile[ty + i][tx] = in[(long)(k0 + ty + i) * N + n0 + tx];
    __syncthreads();
    for (int i = 0; i < 32; i += 8)
        out[(long)(n0 + ty + i) * K + k0 + tx] = f2bf(tile[tx][ty + i]);
}

// ----- V^T extraction: qkv[b,s,2C+h*64+d] -> vt[b,h,d,s]  (bf16) ------------
__global__ __launch_bounds__(256) void k_vt(const short* __restrict__ qkv, short* __restrict__ vt) {
    __shared__ short tile[64][72];
    int bid = blockIdx.x;
    int st = bid & 15, bh = bid >> 4;
    int h = bh & 15, b = bh >> 4;
    int s0 = st * 64;
    int tid = threadIdx.x;
    const short* src = qkv + (size_t)b * SEQ * N3 + 2 * CDIM + h * HD;
    for (int c = tid; c < 512; c += 256) {
        int sr = c >> 3, cg = c & 7;
        *(int4v*)&tile[sr][cg * 8] = *(const int4v*)&src[(size_t)(s0 + sr) * N3 + cg * 8];
    }
    __syncthreads();
    short* dst = vt + (size_t)bh * HD * SEQ + s0;
    for (int c = tid; c < 512; c += 256) {
        int d = c >> 3, sg = c & 7;
        short tmp[8];
#pragma unroll
        for (int j = 0; j < 8; ++j) tmp[j] = tile[sg * 8 + j][d];
        *(int4v*)&dst[(size_t)d * SEQ + sg * 8] = *(const int4v*)tmp;
    }
}

// --------- bf16 GEMM (m97 structure): C = A[M][K] * Bt[N][K]^T + bias -------
template <bool OUT_BF16>
__global__ __launch_bounds__(256) void k_gemm(
    const short* __restrict__ A, const short* __restrict__ Bt,
    const float* __restrict__ bias, void* __restrict__ Cout,
    int M, int N, int K) {
    constexpr int BM = 128, BN = 128, BK = 32;
    __shared__ short As[BM * BK];
    __shared__ short Bs[BN * BK];
    int tid = threadIdx.x;
    int nbn = N / BN;
    int bm = blockIdx.x / nbn, bn = blockIdx.x % nbn;
    int m0 = bm * BM, n0 = bn * BN;
    int w = tid >> 6, l = tid & 63;
    int wm = (w >> 1) * 64, wn = (w & 1) * 64;
    int lr = l & 15, lk = l >> 4;
    f32x4 acc[4][4] = {};
    int rowS = w * 32 + (l >> 2);
    int colS = (l & 3) * 8;
    for (int k0 = 0; k0 < K; k0 += BK) {
        const short* ga = A  + (size_t)(m0 + rowS) * K + k0 + colS;
        const short* gb = Bt + (size_t)(n0 + rowS) * K + k0 + colS;
        gll16(ga,          &As[(w * 32) * BK]);
        gll16(ga + 16 * K, &As[(w * 32 + 16) * BK]);
        gll16(gb,          &Bs[(w * 32) * BK]);
        gll16(gb + 16 * K, &Bs[(w * 32 + 16) * BK]);
        __syncthreads();
        bf16x8 af[4], bfr[4];
#pragma unroll
        for (int mi = 0; mi < 4; ++mi) af[mi]  = *(const bf16x8*)&As[(wm + mi * 16 + lr) * BK + lk * 8];
#pragma unroll
        for (int ni = 0; ni < 4; ++ni) bfr[ni] = *(const bf16x8*)&Bs[(wn + ni * 16 + lr) * BK + lk * 8];
#pragma unroll
        for (int mi = 0; mi < 4; ++mi)
#pragma unroll
            for (int ni = 0; ni < 4; ++ni)
                acc[mi][ni] = __builtin_amdgcn_mfma_f32_16x16x32_bf16(af[mi], bfr[ni], acc[mi][ni], 0, 0, 0);
        __syncthreads();
    }
#pragma unroll
    for (int mi = 0; mi < 4; ++mi)
#pragma unroll
        for (int ni = 0; ni < 4; ++ni) {
            int col = n0 + wn + ni * 16 + lr;
            float bv = bias[col];
#pragma unroll
            for (int r = 0; r < 4; ++r) {
                int row = m0 + wm + mi * 16 + lk * 4 + r;
                float v = acc[mi][ni][r] + bv;
                if (OUT_BF16) ((short*)Cout)[(size_t)row * N + col] = f2bf(v);
                else          ((float*)Cout)[(size_t)row * N + col] = v;
            }
        }
}

// ------------- per-head LayerNorm + RoPE (q,k only) -> [B,H,S,D] ------------
__global__ __launch_bounds__(256) void k_ln_rope(
    const short* __restrict__ qkv,
    const float* __restrict__ qn_w, const float* __restrict__ qn_b,
    const float* __restrict__ kn_w, const float* __restrict__ kn_b,
    const float* __restrict__ fcos, const float* __restrict__ fsin,
    short* __restrict__ q, short* __restrict__ k) {
    int wave = (blockIdx.x * blockDim.x + threadIdx.x) >> 6;
    int lane = threadIdx.x & 63;
    int h = wave & 15;
    int tmp = wave >> 4;
    int which = tmp & 1;
    int bs = tmp >> 1;
    int s = bs & 1023, b = bs >> 10;
    float x = bf2f(qkv[(size_t)bs * N3 + which * CDIM + h * HD + lane]);
    float mu = x;
    for (int o = 32; o > 0; o >>= 1) mu += __shfl_xor(mu, o);
    mu *= (1.f / 64.f);
    float d = x - mu;
    float var = d * d;
    for (int o = 32; o > 0; o >>= 1) var += __shfl_xor(var, o);
    var *= (1.f / 64.f);
    const float* wv = which ? kn_w : qn_w;
    const float* bb = which ? kn_b : qn_b;
    float y = d * rsqrtf(var + 1e-6f) * wv[lane] + bb[lane];
    float c = fcos[s * HD + lane], sn = fsin[s * HD + lane];
    float partner = __shfl_xor(y, 1);
    float rot = (lane & 1) ? partner : -partner;
    y = y * c + rot * sn;
    short* dst = which ? k : q;
    dst[((size_t)(b * NH + h) * SEQ + s) * HD + lane] = f2bf(y);
}

// --- flash attention: 8 waves, QBLK=128, dbuf LDS + async-stage, defer-max --
__global__ __launch_bounds__(512) void k_attn(
    const short* __restrict__ q, const short* __restrict__ k, const short* __restrict__ vt,
    short* __restrict__ out /* [B,S,C] bf16 */) {
    constexpr int KVB = 64;
    constexpr int NT = SEQ / KVB;  // 16
    __shared__ short Ks[2][KVB * 64];   // [kv][d], 128B rows, XOR-swizzled
    __shared__ short Vs[2][64 * KVB];   // [d][kv], 128B rows, XOR-swizzled
    int tid = threadIdx.x, w = tid >> 6, l = tid & 63;
    // XCD swizzle: grid=1024; each head (8 blocks, 256KB K/V) on one XCD L2
    int bid = blockIdx.x;
    int swz = (bid & 7) * 128 + (bid >> 3);
    int bh = swz >> 3;
    int q0 = (swz & 7) * 128;
    const short* qb = q  + (size_t)bh * SEQ * HD;
    const short* kb = k  + (size_t)bh * SEQ * HD;
    const short* vb = vt + (size_t)bh * HD * SEQ;
    int lr = l & 15, lk = l >> 4;
    int qrow = q0 + w * 16 + lr;
    bf16x8 qB[2];
    qB[0] = *(const bf16x8*)&qb[(size_t)qrow * HD + lk * 8];
    qB[1] = *(const bf16x8*)&qb[(size_t)qrow * HD + 32 + lk * 8];
    f32x4 accO[4] = {};
    float m_run = -1e30f, l_run = 0.f;
    int g0 = 2 * (lk & 1);
    bool hi = (lk >> 1) != 0;
    constexpr float SC2 = 0.125f * 1.44269504f;  // scale * log2(e)

    // staging: 512 threads, thread -> one 16B K-chunk + one 16B V-chunk
    int srow = tid >> 3, scg = tid & 7;
    int soff = srow * 128 + ((scg * 16) ^ ((srow & 7) << 4));
    const short* kg = kb + (size_t)srow * HD + scg * 8;   // + t*KVB*HD
    const short* vg = vb + (size_t)srow * SEQ + scg * 8;  // + t*KVB
    int4v kreg = *(const int4v*)kg;
    int4v vreg = *(const int4v*)vg;
    *(int4v*)((char*)Ks[0] + soff) = kreg;
    *(int4v*)((char*)Vs[0] + soff) = vreg;

    for (int t = 0; t < NT; ++t) {
        __syncthreads();                       // staged writes for tile t visible
        int cur = t & 1;
        if (t + 1 < NT) {                      // issue next tile's loads early
            kreg = *(const int4v*)(kg + (size_t)(t + 1) * KVB * HD);
            vreg = *(const int4v*)(vg + (t + 1) * KVB);
        }
        // S^T[kv][q] = K Q^T
        f32x4 sc[4];
#pragma unroll
        for (int nf = 0; nf < 4; ++nf) {
            f32x4 a = {};
#pragma unroll
            for (int ks = 0; ks < 2; ++ks) {
                int row = nf * 16 + lr;
                bf16x8 kf = *(const bf16x8*)((const char*)Ks[cur] + row * 128 +
                                             ((ks * 64 + lk * 16) ^ ((row & 7) << 4)));
                a = __builtin_amdgcn_mfma_f32_16x16x32_bf16(kf, qB[ks], a, 0, 0, 0);
            }
            sc[nf] = a;
        }
        // online softmax in log2 domain, defer-max (THR=8 -> p <= 256)
        float t2[4][4];
        float mt = -1e30f;
#pragma unroll
        for (int nf = 0; nf < 4; ++nf)
#pragma unroll
            for (int r = 0; r < 4; ++r) { t2[nf][r] = sc[nf][r] * SC2; mt = fmaxf(mt, t2[nf][r]); }
        mt = fmaxf(mt, __shfl_xor(mt, 16));
        mt = fmaxf(mt, __shfl_xor(mt, 32));
        if (!__all(mt - m_run <= 8.f)) {
            float mn = fmaxf(m_run, mt);
            float alpha = exp2_hw(m_run - mn);  // first tile: exp2(-inf)=0
            l_run *= alpha;
#pragma unroll
            for (int df = 0; df < 4; ++df)
#pragma unroll
                for (int r = 0; r < 4; ++r) accO[df][r] *= alpha;
            m_run = mn;
        }
        float ps[4][4];
        float ls = 0.f;
#pragma unroll
        for (int nf = 0; nf < 4; ++nf)
#pragma unroll
            for (int r = 0; r < 4; ++r) { ps[nf][r] = exp2_hw(t2[nf][r] - m_run); ls += ps[nf][r]; }
        ls += __shfl_xor(ls, 16);
        ls += __shfl_xor(ls, 32);
        l_run += ls;
        // pack P to bf16 words: pwd[nf][jj] = kv {16nf+4lk+2jj, +1} for q=lr
        unsigned pwd[4][2];
#pragma unroll
        for (int nf = 0; nf < 4; ++nf)
#pragma unroll
            for (int jj = 0; jj < 2; ++jj)
                pwd[nf][jj] = (unsigned)(unsigned short)f2bf(ps[nf][2 * jj]) |
                              ((unsigned)(unsigned short)f2bf(ps[nf][2 * jj + 1]) << 16);
        // PV: O^T[d][q] += V^T P ; P B-frags via register shuffles
#pragma unroll
        for (int c = 0; c < 2; ++c) {
            unsigned wds[4];
#pragma unroll
            for (int w2 = 0; w2 < 4; ++w2) {
                int src = lr + 16 * (g0 + (w2 >> 1));
                unsigned a0 = (unsigned)__shfl((int)pwd[2 * c][w2 & 1], src);
                unsigned a1 = (unsigned)__shfl((int)pwd[2 * c + 1][w2 & 1], src);
                wds[w2] = hi ? a1 : a0;
            }
            int4v wi = { (int)wds[0], (int)wds[1], (int)wds[2], (int)wds[3] };
            bf16x8 pf = __builtin_bit_cast(bf16x8, wi);
#pragma unroll
            for (int df = 0; df < 4; ++df) {
                int row = df * 16 + lr;
                bf16x8 vf = *(const bf16x8*)((const char*)Vs[cur] + row * 128 +
                                             ((c * 64 + lk * 16) ^ ((row & 7) << 4)));
                accO[df] = __builtin_amdgcn_mfma_f32_16x16x32_bf16(vf, pf, accO[df], 0, 0, 0);
            }
        }
        if (t + 1 < NT) {                      // write next tile (other buffer)
            *(int4v*)((char*)Ks[cur ^ 1] + soff) = kreg;
            *(int4v*)((char*)Vs[cur ^ 1] + soff) = vreg;
        }
    }
    // epilogue: accO[df][r] = O^T[d = df*16 + lk*4 + r][q = q0 + w*16 + lr]
    float inv = 1.f / l_run;
    int b = bh >> 4, h = bh & 15;
    int qg = q0 + w * 16 + lr;
#pragma unroll
    for (int df = 0; df < 4; ++df) {
        short4v o4;
#pragma unroll
        for (int r = 0; r < 4; ++r) o4[r] = f2bf(accO[df][r] * inv);
        *(short4v*)&out[((size_t)(b * SEQ + qg)) * CDIM + h * HD + df * 16 + lk * 4] = o4;
    }
}

extern "C" void kernel_launch(void* const* d_in, const int* in_sizes, int n_in,
                              void* d_out, int out_size, void* d_ws, size_t ws_size,
                              hipStream_t stream) {
    const float* hidden = (const float*)d_in[0];
    const float* W_qkv  = (const float*)d_in[1];
    const float* b_qkv  = (const float*)d_in[2];
    const float* qn_w   = (const float*)d_in[3];
    const float* qn_b   = (const float*)d_in[4];
    const float* kn_w   = (const float*)d_in[5];
    const float* kn_b   = (const float*)d_in[6];
    const float* W_proj = (const float*)d_in[7];
    const float* b_proj = (const float*)d_in[8];
    const float* fcos   = (const float*)d_in[9];
    const float* fsin   = (const float*)d_in[10];
    float* out = (float*)d_out;

    const size_t SZ_HBF    = (size_t)BATCH * SEQ * CDIM * 2;
    const size_t SZ_WQKVT  = (size_t)N3 * CDIM * 2;
    const size_t SZ_WPROJT = (size_t)CDIM * CDIM * 2;
    const size_t SZ_QKV    = (size_t)BATCH * SEQ * N3 * 2;
    const size_t SZ_HEAD   = (size_t)BATCH * NH * SEQ * HD * 2;

    char* ws = (char*)d_ws;
    short* hbf    = (short*)ws; ws += SZ_HBF;
    short* wqkvT  = (short*)ws; ws += SZ_WQKVT;
    short* wprojT = (short*)ws; ws += SZ_WPROJT;
    short* qkv    = (short*)ws; ws += SZ_QKV;
    short* qh     = (short*)ws; ws += SZ_HEAD;
    short* kh     = (short*)ws; ws += SZ_HEAD;
    short* vt     = (short*)ws; ws += SZ_HEAD;
    short* attn_o = hbf;  // alias: hbf dead after GEMM1

    size_t needed = SZ_HBF + SZ_WQKVT + SZ_WPROJT + SZ_QKV + 3 * SZ_HEAD;
    if (ws_size < needed) return;

    int nHid = BATCH * SEQ * CDIM;
    k_f32_to_bf16<<<nHid / 8 / 256, 256, 0, stream>>>(hidden, hbf, nHid);
    k_transpose_f32_to_bf16<<<dim3(N3 / 32, CDIM / 32), dim3(32, 8), 0, stream>>>(W_qkv, wqkvT, CDIM, N3);
    k_transpose_f32_to_bf16<<<dim3(CDIM / 32, CDIM / 32), dim3(32, 8), 0, stream>>>(W_proj, wprojT, CDIM, CDIM);

    // GEMM1: qkv = hidden @ W_qkv + b_qkv   [8192 x 3072]
    k_gemm<true><<<(BATCH * SEQ / 128) * (N3 / 128), 256, 0, stream>>>(
        hbf, wqkvT, b_qkv, qkv, BATCH * SEQ, N3, CDIM);

    // LN + RoPE for q,k -> [B,H,S,D]; V^T extracted separately
    int nWaves = BATCH * SEQ * 2 * NH;
    k_ln_rope<<<nWaves / 4, 256, 0, stream>>>(qkv, qn_w, qn_b, kn_w, kn_b, fcos, fsin, qh, kh);
    k_vt<<<BATCH * NH * (SEQ / 64), 256, 0, stream>>>(qkv, vt);

    // attention: QBLK=128, 8 waves
    k_attn<<<BATCH * NH * (SEQ / 128), 512, 0, stream>>>(qh, kh, vt, attn_o);

    // GEMM2: out = attn_o @ W_proj + b_proj  [8192 x 1024] fp32
    k_gemm<false><<<(BATCH * SEQ / 128) * (CDIM / 128), 256, 0, stream>>>(
        attn_o, wprojT, b_proj, out, BATCH * SEQ, CDIM, CDIM);
}